// Round 3
// baseline (143.998 us; speedup 1.0000x reference)
//
#include <hip/hip_runtime.h>

#define H_ 8
#define D_ 128
#define KD_ 16
#define E_ 128
#define B_ 16
#define G_ 501
#define NP_ 250
#define BN_ (B_*G_)   // 8016

typedef __bf16 bf16x8 __attribute__((ext_vector_type(8)));
typedef float f32x4 __attribute__((ext_vector_type(4)));
typedef unsigned short u16x8 __attribute__((ext_vector_type(8)));
typedef unsigned short u16x4 __attribute__((ext_vector_type(4)));
typedef bf16x8 __attribute__((may_alias)) bf16x8_a;
typedef u16x8 __attribute__((may_alias)) u16x8_a;
typedef u16x4 __attribute__((may_alias)) u16x4_a;

__device__ __forceinline__ unsigned short f2bf(float f) {
  unsigned int u = __builtin_bit_cast(unsigned int, f);
  unsigned int r = u + 0x7FFFu + ((u >> 16) & 1u);
  return (unsigned short)(r >> 16);
}
__device__ __forceinline__ float bf2f(unsigned short u) {
  unsigned int v = ((unsigned int)u) << 16;
  return __builtin_bit_cast(float, v);
}

// ---------------- K0: build WcT[c=(h,w,k)][d] bf16 from fp32 weights ----------------
__global__ __launch_bounds__(256) void k_prep(
    const float* __restrict__ w0, const float* __restrict__ w1, const float* __restrict__ w2,
    const float* __restrict__ w3, const float* __restrict__ w4, const float* __restrict__ w5,
    const float* __restrict__ w6, const float* __restrict__ w7, const float* __restrict__ w8,
    unsigned short* __restrict__ wct) {
  int i = blockIdx.x * 256 + threadIdx.x;
  if (i < H_*9*KD_*D_) {
    int d = i & 127; int t = i >> 7; int k = t & 15; t >>= 4;
    int wi = t % 9; int h = t / 9;
    const float* src = w0;
    switch (wi) {
      case 1: src = w1; break; case 2: src = w2; break; case 3: src = w3; break;
      case 4: src = w4; break; case 5: src = w5; break; case 6: src = w6; break;
      case 7: src = w7; break; case 8: src = w8; break; default: break;
    }
    wct[i] = f2bf(src[h*(D_*KD_) + d*KD_ + k]);
  }
}

// ---------------- K1: P[(h,w,b)][n][kd] = q @ Wcat, LDS-staged MFMA GEMM ----------
// grid (18, 128); block 256. Query-type projections (w != 1,2) pre-scaled by 0.25.
__global__ __launch_bounds__(256) void k_proj(const float* __restrict__ q,
                                              const unsigned short* __restrict__ wct,
                                              unsigned short* __restrict__ P) {
  const int tid = threadIdx.x;
  const int lane = tid & 63;
  const int wv = tid >> 6;
  const int ln = lane & 15;
  const int quad = lane >> 4;
  const int b = blockIdx.y >> 3;
  const int nt = blockIdx.y & 7;
  const int cbase = blockIdx.x * 64;

  __shared__ __align__(16) unsigned short sA[64*136];
  __shared__ __align__(16) unsigned short sB[64*136];

  for (int i = tid; i < 1024; i += 256) {          // A: 64 rows x 128 d (fp32 -> bf16)
    int rr = i >> 4, half = i & 15;
    int r = min(nt*64 + rr, G_ - 1);
    const float* src = q + (size_t)(b*G_ + r)*D_ + half*8;
    float4 f0 = ((const float4*)src)[0];
    float4 f1 = ((const float4*)src)[1];
    u16x8 v;
    v[0]=f2bf(f0.x); v[1]=f2bf(f0.y); v[2]=f2bf(f0.z); v[3]=f2bf(f0.w);
    v[4]=f2bf(f1.x); v[5]=f2bf(f1.y); v[6]=f2bf(f1.z); v[7]=f2bf(f1.w);
    *(u16x8*)(sA + rr*136 + half*8) = v;
  }
  for (int i = tid; i < 1024; i += 256) {          // B: 64 cols x 128 d
    int cc = i >> 4, half = i & 15;
    u16x8 v = *(const u16x8*)(wct + (size_t)(cbase + cc)*D_ + half*8);
    *(u16x8*)(sB + cc*136 + half*8) = v;
  }
  __syncthreads();

  bf16x8 a[4];
  #pragma unroll
  for (int ks = 0; ks < 4; ++ks)
    a[ks] = *(const bf16x8_a*)(sA + (wv*16 + ln)*136 + ks*32 + quad*8);

  #pragma unroll
  for (int ct = 0; ct < 4; ++ct) {
    f32x4 acc = {0.f,0.f,0.f,0.f};
    #pragma unroll
    for (int ks = 0; ks < 4; ++ks) {
      bf16x8 bb = *(const bf16x8_a*)(sB + (ct*16 + ln)*136 + ks*32 + quad*8);
      acc = __builtin_amdgcn_mfma_f32_16x16x32_bf16(a[ks], bb, acc, 0,0,0);
    }
    const int c = cbase + ct*16 + ln;
    const int h = c / 144; const int rem = c - h*144; const int w = rem >> 4; const int k = rem & 15;
    const float sc = (w == 1 || w == 2) ? 1.0f : 0.25f;   // fold norm=1/sqrt(KD) into Q-type
    const size_t pb = ((size_t)((h*9 + w)*B_ + b)*G_)*KD_ + k;
    #pragma unroll
    for (int g = 0; g < 4; ++g) {
      const int nn = nt*64 + wv*16 + quad*4 + g;
      if (nn < G_) P[pb + (size_t)nn*KD_] = f2bf(acc[g]*sc);
    }
  }
}

// ---------------- K2: fused heterogeneous attention (S^T orientation) ----------------
// grid = (rt=8, b=16, h=8); block 256 (4 waves x 16 rows). ~52.4 KB LDS -> 3 blocks/CU.
__device__ __forceinline__ f32x4 mf(bf16x8 a, bf16x8 b, f32x4 c) {
  return __builtin_amdgcn_mfma_f32_16x16x32_bf16(a, b, c, 0,0,0);
}

// Compute E^T for one 32-key chunk and write to this wave's eBuf slot.
__device__ __forceinline__ void score_chunk(
    int c, bool up, bool dn, int cbuf,
    const unsigned short* sK, bf16x8 qa, bf16x8 qp, bf16x8 qdl,
    unsigned short* eb, float rv, float& esum, int ln, int quad)
{
  const f32x4 z4 = {0.f,0.f,0.f,0.f};
  bf16x8 k0 = {}, k1 = {};
  if (quad < 2) {                       // kd 0..15 live in quads 0,1 (A k=quad*8+j)
    const unsigned short* kp = sK + (c*32 + ln)*16 + quad*8;
    k0 = *(const bf16x8_a*)(kp);
    k1 = *(const bf16x8_a*)(kp + 256);  // +16 keys
  }
  f32x4 sa0 = mf(k0, qa, z4), sa1 = mf(k1, qa, z4);
  f32x4 sp0 = z4, sp1 = z4, sd0 = z4, sd1 = z4;
  if (up) { sp0 = mf(k0, qp, z4);  sp1 = mf(k1, qp, z4); }
  if (dn) { sd0 = mf(k0, qdl, z4); sd1 = mf(k1, qdl, z4); }

  float el = 0.f;
  unsigned short ev[8];
  #pragma unroll
  for (int t = 0; t < 2; ++t) {
    #pragma unroll
    for (int rg = 0; rg < 4; ++rg) {
      // key = c*32 + t*16 + quad*4 + rg ; lane's attention row = ln
      float comp = __expf(t ? sa1[rg] : sa0[rg]);
      if (c == 15 && t == 1) comp *= (quad*4 + rg <= 4) ? 1.f : 0.f;  // key<=500
      float ex = 0.f;
      if (up) {
        float m = 1.f;
        if (c == 0 && t == 0 && rg == 0) m = (quad != 0) ? 1.f : 0.f;  // key>=1
        if (c == 7 && t == 1) m = (quad*4 + rg <= 10) ? 1.f : 0.f;     // key<=250
        ex += m * __expf(t ? sp1[rg] : sp0[rg]);
      }
      if (dn) {
        float m = 1.f;
        if (c == 7)  m = (t == 1 && quad*4 + rg >= 11) ? 1.f : 0.f;    // key>=251
        if (c == 15 && t == 1) m = (quad*4 + rg <= 4) ? 1.f : 0.f;     // key<=500
        ex += m * __expf(t ? sd1[rg] : sd0[rg]);
      }
      float e = comp + rv * ex;
      el += e;
      ev[t*4 + rg] = f2bf(e);
    }
  }
  esum += el;
  u16x4 w0, w1;
  w0[0]=ev[0]; w0[1]=ev[1]; w0[2]=ev[2]; w0[3]=ev[3];
  w1[0]=ev[4]; w1[1]=ev[5]; w1[2]=ev[6]; w1[3]=ev[7];
  unsigned short* base = eb + cbuf*640 + ln*40 + quad*4;
  *(u16x4_a*)(base)      = w0;   // keys t=0: offset quad*4
  *(u16x4_a*)(base + 16) = w1;   // keys t=1
}

__global__ __launch_bounds__(256, 3) void k_attn(const unsigned short* __restrict__ P,
                                                 float* __restrict__ heads) {
  const int rt = blockIdx.x, b = blockIdx.y, h = blockIdx.z;
  const int tid = threadIdx.x;
  const int lane = tid & 63;
  const int wv = tid >> 6;
  const int ln = lane & 15;
  const int quad = lane >> 4;
  const int r0 = rt * 64;

  __shared__ __align__(16) unsigned short sK [512*16];   // [key][kd], keys>=501 zero
  __shared__ __align__(16) unsigned short sVt[16*520];   // [kd][key], keys>=501 zero
  __shared__ __align__(16) unsigned short sQa[65*16];    // [row][kd] + overread pad
  __shared__ __align__(16) unsigned short sQp[65*16];
  __shared__ __align__(16) unsigned short sQd[65*16];
  __shared__ __align__(16) unsigned short sQs[65*16];
  __shared__ __align__(16) unsigned short sKs[65*16];
  __shared__ __align__(16) unsigned short eBuf[4*2*640]; // per-wave double-buffered E^T

  const size_t slab = (size_t)G_*KD_;
  const unsigned short* Pk = P + ((size_t)(h*9+1)*B_ + b)*slab;
  const unsigned short* Pv = P + ((size_t)(h*9+2)*B_ + b)*slab;
  const u16x8 vz = {0,0,0,0,0,0,0,0};

  for (int i = tid; i < 1024; i += 256) {      // sK: 512 keys x 16
    int key = i >> 1;
    u16x8 v = vz;
    if (key < G_) v = *(const u16x8*)(Pk + key*KD_ + (i & 1)*8);
    *(u16x8*)(sK + i*8) = v;
  }
  for (int i = tid; i < 8192; i += 256) {      // sVt: transpose scatter [kd][key]
    int key = i >> 4, kd = i & 15;
    sVt[kd*520 + key] = (key < G_) ? Pv[key*KD_ + kd] : (unsigned short)0;
  }
  for (int i = tid; i < 650; i += 256) {       // 5 arrays x 130 8-short chunks
    int arr = i / 130;
    int j = i - arr*130;
    int rr = j >> 1, half = j & 1;
    int r = r0 + rr;
    u16x8 v = vz;
    if (rr < 64 && r < G_) {
      bool pick = (r <= NP_);
      const unsigned short* src;
      if (arr == 4) {
        int ks = (r == 0) ? 0 : (pick ? r + NP_ : r - NP_);
        src = Pk + ks*KD_;
      } else {
        int w = (arr == 0) ? 0 : (arr == 1) ? (pick ? 4 : 8)
              : (arr == 2) ? (pick ? 5 : 7) : (pick ? 3 : 6);
        src = P + ((size_t)(h*9 + w)*B_ + b)*slab + (size_t)r*KD_;
      }
      v = *(const u16x8*)(src + half*8);
    }
    unsigned short* dst = (arr==0) ? sQa : (arr==1) ? sQp : (arr==2) ? sQd
                        : (arr==3) ? sQs : sKs;
    *(u16x8*)(dst + j*8) = v;
  }
  __syncthreads();

  // Q fragments as B operand: B[k=quad*8+j][n=ln] = Q[row=wv*16+ln][kd]; quads 2,3
  // read pad garbage that is annihilated by the zeroed K A-fragments.
  const int aoff = (wv*16 + ln)*16 + quad*8;
  bf16x8 qa  = *(const bf16x8_a*)(sQa + aoff);
  bf16x8 qp  = *(const bf16x8_a*)(sQp + aoff);
  bf16x8 qdl = *(const bf16x8_a*)(sQd + aoff);

  const int rw0 = r0 + wv*16;
  const int ra = rw0 + ln;                     // this lane's attention row
  const float rv = (ra >= 1) ? 1.f : 0.f;
  unsigned short* eb = eBuf + wv*1280;

  f32x4 acc = {0.f,0.f,0.f,0.f};
  float esum = 0.f;

  #pragma unroll
  for (int p = 0; p < 8; ++p) {
    const int c0 = 2*p, c1 = c0 + 1;
    score_chunk(c0, c0 <= 7, c0 >= 7, 0, sK, qa, qp, qdl, eb, rv, esum, ln, quad);
    score_chunk(c1, c1 <= 7, c1 >= 7, 1, sK, qa, qp, qdl, eb, rv, esum, ln, quad);
    #pragma unroll
    for (int u = 0; u < 2; ++u) {
      bf16x8 Ef = *(const bf16x8_a*)(eb + u*640 + ln*40 + quad*8);
      bf16x8 Vf = *(const bf16x8_a*)(sVt + ln*520 + (c0+u)*32 + quad*8);
      acc = mf(Vf, Ef, acc);                   // O^T[kd][row] += V^T * E^T
    }
  }

  // esum: keys are spread across quads -> reduce across the 4 quads (rows = ln fixed)
  esum += __shfl_xor(esum, 16);
  esum += __shfl_xor(esum, 32);

  // paired single score: 16-elem dot per row (computed redundantly in each quad)
  const unsigned short* qsp = sQs + (wv*16 + ln)*16;
  const unsigned short* ksp = sKs + (wv*16 + ln)*16;
  u16x8 qs0 = *(const u16x8_a*)(qsp), qs1 = *(const u16x8_a*)(qsp + 8);
  u16x8 ks0 = *(const u16x8_a*)(ksp), ks1 = *(const u16x8_a*)(ksp + 8);
  float s = 0.f;
  #pragma unroll
  for (int kd = 0; kd < 8; ++kd) {
    s = fmaf(bf2f(qs0[kd]), bf2f(ks0[kd]), s);
    s = fmaf(bf2f(qs1[kd]), bf2f(ks1[kd]), s);
  }
  const float rvs = (ra >= 1 && ra < G_) ? 1.f : 0.f;
  const float esng = rvs * __expf(s);
  esum += esng;
  const int kpair = (ra >= 1 && ra < G_) ? ((ra <= NP_) ? ra + NP_ : ra - NP_) : 0;

  const float rcp = __builtin_amdgcn_rcpf(esum);
  float4 o;
  o.x = (acc[0] + esng * bf2f(sVt[(quad*4+0)*520 + kpair])) * rcp;
  o.y = (acc[1] + esng * bf2f(sVt[(quad*4+1)*520 + kpair])) * rcp;
  o.z = (acc[2] + esng * bf2f(sVt[(quad*4+2)*520 + kpair])) * rcp;
  o.w = (acc[3] + esng * bf2f(sVt[(quad*4+3)*520 + kpair])) * rcp;
  if (ra < G_)
    *(float4*)(heads + ((size_t)(b*G_ + ra))*E_ + h*16 + quad*4) = o;
}

// ---------------- K3: out = heads(8016x128) @ W_out(128x128), fp32 ----------------
__global__ __launch_bounds__(256) void k_out(const float* __restrict__ heads,
                                             const float* __restrict__ wout,
                                             float* __restrict__ out) {
  const int base = blockIdx.x * 16;
  const int tid = threadIdx.x;
  __shared__ __align__(16) float sA[16*128];
  for (int i = tid; i < 512; i += 256)
    ((float4*)sA)[i] = ((const float4*)heads)[(size_t)base*32 + i];
  __syncthreads();
  const int cg = tid & 31, rh = tid >> 5;
  float4 acc0 = make_float4(0.f,0.f,0.f,0.f);
  float4 acc1 = make_float4(0.f,0.f,0.f,0.f);
  const float4* w4 = (const float4*)wout;
  #pragma unroll 8
  for (int kk = 0; kk < 128; ++kk) {
    float4 wv = w4[kk*32 + cg];
    float a0 = sA[(rh*2)*128 + kk];
    float a1 = sA[(rh*2+1)*128 + kk];
    acc0.x = fmaf(a0, wv.x, acc0.x); acc0.y = fmaf(a0, wv.y, acc0.y);
    acc0.z = fmaf(a0, wv.z, acc0.z); acc0.w = fmaf(a0, wv.w, acc0.w);
    acc1.x = fmaf(a1, wv.x, acc1.x); acc1.y = fmaf(a1, wv.y, acc1.y);
    acc1.z = fmaf(a1, wv.z, acc1.z); acc1.w = fmaf(a1, wv.w, acc1.w);
  }
  ((float4*)out)[(size_t)(base + rh*2)*32 + cg] = acc0;
  ((float4*)out)[(size_t)(base + rh*2 + 1)*32 + cg] = acc1;
}

extern "C" void kernel_launch(void* const* d_in, const int* in_sizes, int n_in,
                              void* d_out, int out_size, void* d_ws, size_t ws_size,
                              hipStream_t stream) {
  const float* q = (const float*)d_in[0];
  const float* w0 = (const float*)d_in[1];
  const float* w1 = (const float*)d_in[2];
  const float* w2 = (const float*)d_in[3];
  const float* w3 = (const float*)d_in[4];
  const float* w4 = (const float*)d_in[5];
  const float* w5 = (const float*)d_in[6];
  const float* w6 = (const float*)d_in[7];
  const float* w7 = (const float*)d_in[8];
  const float* w8 = (const float*)d_in[9];
  const float* wout = (const float*)d_in[10];
  float* out = (float*)d_out;

  char* ws = (char*)d_ws;
  unsigned short* wct = (unsigned short*)(ws);                 // 1152*128*2 = 294,912
  unsigned short* P   = (unsigned short*)(ws + 294912);        // 72*16*501*16*2 = 18,468,864
  float* heads        = (float*)(ws + 18763776);               // 8016*128*4 = 4,104,192

  k_prep<<<dim3(4608), dim3(256), 0, stream>>>(w0,w1,w2,w3,w4,w5,w6,w7,w8, wct);
  k_proj<<<dim3(18, 128), dim3(256), 0, stream>>>(q, wct, P);
  k_attn<<<dim3(8, 16, 8), dim3(256), 0, stream>>>(P, heads);
  k_out<<<dim3(501), dim3(256), 0, stream>>>(heads, wout, out);
}

// Round 4
// 123.397 us; speedup vs baseline: 1.1669x; 1.1669x over previous
//
#include <hip/hip_runtime.h>

#define H_ 8
#define D_ 128
#define KD_ 16
#define E_ 128
#define B_ 16
#define G_ 501
#define NP_ 250
#define BN_ (B_*G_)   // 8016

typedef __bf16 bf16x8 __attribute__((ext_vector_type(8)));
typedef float f32x4 __attribute__((ext_vector_type(4)));
typedef unsigned short u16x8 __attribute__((ext_vector_type(8)));
typedef unsigned short u16x4 __attribute__((ext_vector_type(4)));
typedef bf16x8 __attribute__((may_alias)) bf16x8_a;
typedef u16x8 __attribute__((may_alias)) u16x8_a;
typedef u16x4 __attribute__((may_alias)) u16x4_a;

__device__ __forceinline__ unsigned short f2bf(float f) {
  unsigned int u = __builtin_bit_cast(unsigned int, f);
  unsigned int r = u + 0x7FFFu + ((u >> 16) & 1u);
  return (unsigned short)(r >> 16);
}
__device__ __forceinline__ float bf2f(unsigned short u) {
  unsigned int v = ((unsigned int)u) << 16;
  return __builtin_bit_cast(float, v);
}

// ---------------- K0: build WcT[c=(h,w,k)][d] bf16; zero Pvt pad keys ----------------
__global__ __launch_bounds__(256) void k_prep(
    const float* __restrict__ w0, const float* __restrict__ w1, const float* __restrict__ w2,
    const float* __restrict__ w3, const float* __restrict__ w4, const float* __restrict__ w5,
    const float* __restrict__ w6, const float* __restrict__ w7, const float* __restrict__ w8,
    unsigned short* __restrict__ wct, unsigned short* __restrict__ Pvt) {
  int i = blockIdx.x * 256 + threadIdx.x;
  if (i < H_*9*KD_*D_) {
    int d = i & 127; int t = i >> 7; int k = t & 15; t >>= 4;
    int wi = t % 9; int h = t / 9;
    const float* src = w0;
    switch (wi) {
      case 1: src = w1; break; case 2: src = w2; break; case 3: src = w3; break;
      case 4: src = w4; break; case 5: src = w5; break; case 6: src = w6; break;
      case 7: src = w7; break; case 8: src = w8; break; default: break;
    }
    wct[i] = f2bf(src[h*(D_*KD_) + d*KD_ + k]);
  }
  if (i < 128*16*19) {            // zero Pvt keys 501..519 for all (h,b) x kd
    int s = i / 304; int r2 = i - s*304; int k = r2 / 19; int key = 501 + (r2 - k*19);
    Pvt[(size_t)s*8320 + k*520 + key] = 0;
  }
}

// ---------------- K1: P[(h,w,b)][n][kd] = q @ Wcat (V routed transposed to Pvt) ------
// grid (18, 128); block 256. Query-type projections (w != 1,2) pre-scaled by 0.25.
__global__ __launch_bounds__(256) void k_proj(const float* __restrict__ q,
                                              const unsigned short* __restrict__ wct,
                                              unsigned short* __restrict__ P,
                                              unsigned short* __restrict__ Pvt) {
  const int tid = threadIdx.x;
  const int lane = tid & 63;
  const int wv = tid >> 6;
  const int ln = lane & 15;
  const int quad = lane >> 4;
  const int b = blockIdx.y >> 3;
  const int nt = blockIdx.y & 7;
  const int cbase = blockIdx.x * 64;

  __shared__ __align__(16) unsigned short sA[64*136];
  __shared__ __align__(16) unsigned short sB[64*136];

  for (int i = tid; i < 1024; i += 256) {          // A: 64 rows x 128 d (fp32 -> bf16)
    int rr = i >> 4, half = i & 15;
    int r = min(nt*64 + rr, G_ - 1);
    const float* src = q + (size_t)(b*G_ + r)*D_ + half*8;
    float4 f0 = ((const float4*)src)[0];
    float4 f1 = ((const float4*)src)[1];
    u16x8 v;
    v[0]=f2bf(f0.x); v[1]=f2bf(f0.y); v[2]=f2bf(f0.z); v[3]=f2bf(f0.w);
    v[4]=f2bf(f1.x); v[5]=f2bf(f1.y); v[6]=f2bf(f1.z); v[7]=f2bf(f1.w);
    *(u16x8*)(sA + rr*136 + half*8) = v;
  }
  for (int i = tid; i < 1024; i += 256) {          // B: 64 cols x 128 d
    int cc = i >> 4, half = i & 15;
    u16x8 v = *(const u16x8*)(wct + (size_t)(cbase + cc)*D_ + half*8);
    *(u16x8*)(sB + cc*136 + half*8) = v;
  }
  __syncthreads();

  bf16x8 a[4];
  #pragma unroll
  for (int ks = 0; ks < 4; ++ks)
    a[ks] = *(const bf16x8_a*)(sA + (wv*16 + ln)*136 + ks*32 + quad*8);

  #pragma unroll
  for (int ct = 0; ct < 4; ++ct) {
    f32x4 acc = {0.f,0.f,0.f,0.f};
    #pragma unroll
    for (int ks = 0; ks < 4; ++ks) {
      bf16x8 bb = *(const bf16x8_a*)(sB + (ct*16 + ln)*136 + ks*32 + quad*8);
      acc = __builtin_amdgcn_mfma_f32_16x16x32_bf16(a[ks], bb, acc, 0,0,0);
    }
    const int c = cbase + ct*16 + ln;
    const int h = c / 144; const int rem = c - h*144; const int w = rem >> 4; const int k = rem & 15;
    if (w == 2) {                                  // V: transposed layout [kd][key]
      unsigned short* dstv = Pvt + (size_t)(h*B_ + b)*8320 + k*520;
      #pragma unroll
      for (int g = 0; g < 4; ++g) {
        const int nn = nt*64 + wv*16 + quad*4 + g;
        if (nn < G_) dstv[nn] = f2bf(acc[g]);
      }
    } else {
      const float sc = (w == 1) ? 1.0f : 0.25f;    // fold norm into Q-type streams
      const size_t pb = ((size_t)((h*9 + w)*B_ + b)*G_)*KD_ + k;
      #pragma unroll
      for (int g = 0; g < 4; ++g) {
        const int nn = nt*64 + wv*16 + quad*4 + g;
        if (nn < G_) P[pb + (size_t)nn*KD_] = f2bf(acc[g]*sc);
      }
    }
  }
}

// ---------------- K2: fused heterogeneous attention (S^T, 2 row-tiles/block) --------
__device__ __forceinline__ f32x4 mf(bf16x8 a, bf16x8 b, f32x4 c) {
  return __builtin_amdgcn_mfma_f32_16x16x32_bf16(a, b, c, 0,0,0);
}

__device__ __forceinline__ void score_chunk(
    int c, bool up, bool dn, int cbuf,
    const unsigned short* sK, bf16x8 qa, bf16x8 qp, bf16x8 qdl,
    unsigned short* eb, float rv, float& esum, int ln, int quad)
{
  const f32x4 z4 = {0.f,0.f,0.f,0.f};
  bf16x8 k0 = {}, k1 = {};
  if (quad < 2) {                       // kd 0..15 live in quads 0,1
    const unsigned short* kp = sK + (c*32 + ln)*24 + quad*8;
    k0 = *(const bf16x8_a*)(kp);
    k1 = *(const bf16x8_a*)(kp + 384);  // +16 keys (stride 24)
  }
  f32x4 sa0 = mf(k0, qa, z4), sa1 = mf(k1, qa, z4);
  f32x4 sp0 = z4, sp1 = z4, sd0 = z4, sd1 = z4;
  if (up) { sp0 = mf(k0, qp, z4);  sp1 = mf(k1, qp, z4); }
  if (dn) { sd0 = mf(k0, qdl, z4); sd1 = mf(k1, qdl, z4); }

  float el = 0.f;
  unsigned short ev[8];
  #pragma unroll
  for (int t = 0; t < 2; ++t) {
    #pragma unroll
    for (int rg = 0; rg < 4; ++rg) {
      // key = c*32 + t*16 + quad*4 + rg ; lane's attention row index = ln
      float comp = __expf(t ? sa1[rg] : sa0[rg]);
      if (c == 15 && t == 1) comp *= (quad*4 + rg <= 4) ? 1.f : 0.f;   // key<=500
      float ex = 0.f;
      if (up) {
        float m = 1.f;
        if (c == 0 && t == 0 && rg == 0) m = (quad != 0) ? 1.f : 0.f;  // key>=1
        if (c == 7 && t == 1) m = (quad*4 + rg <= 10) ? 1.f : 0.f;     // key<=250
        ex += m * __expf(t ? sp1[rg] : sp0[rg]);
      }
      if (dn) {
        float m = 1.f;
        if (c == 7)  m = (t == 1 && quad*4 + rg >= 11) ? 1.f : 0.f;    // key>=251
        if (c == 15 && t == 1) m = (quad*4 + rg <= 4) ? 1.f : 0.f;     // key<=500
        ex += m * __expf(t ? sd1[rg] : sd0[rg]);
      }
      float e = comp + rv * ex;
      el += e;
      ev[t*4 + rg] = f2bf(e);
    }
  }
  esum += el;
  u16x4 w0, w1;
  w0[0]=ev[0]; w0[1]=ev[1]; w0[2]=ev[2]; w0[3]=ev[3];
  w1[0]=ev[4]; w1[1]=ev[5]; w1[2]=ev[6]; w1[3]=ev[7];
  unsigned short* base = eb + cbuf*640 + ln*40 + quad*4;
  *(u16x4_a*)(base)      = w0;
  *(u16x4_a*)(base + 16) = w1;
}

// grid = (rt2=4, b=16, h=8) = 512 blocks; block 256; 2 blocks/CU, no tail round.
__global__ __launch_bounds__(256, 2) void k_attn(const unsigned short* __restrict__ P,
                                                 const unsigned short* __restrict__ Pvt,
                                                 unsigned short* __restrict__ headsb) {
  const int rt2 = blockIdx.x, b = blockIdx.y, h = blockIdx.z;
  const int tid = threadIdx.x;
  const int lane = tid & 63;
  const int wv = tid >> 6;
  const int ln = lane & 15;
  const int quad = lane >> 4;

  __shared__ __align__(16) unsigned short sK [512*24];   // [key][kd] stride 24
  __shared__ __align__(16) unsigned short sVt[16*520];   // [kd][key]
  __shared__ __align__(16) unsigned short sQ [8*1040];   // [t][arr(a,p,d,s)][65*16]
  __shared__ __align__(16) unsigned short eBuf[4*2*640]; // per-wave double-buffered E^T

  const size_t slab = (size_t)G_*KD_;
  const unsigned short* Pk = P + ((size_t)(h*9+1)*B_ + b)*slab;
  const u16x8 vz = {0,0,0,0,0,0,0,0};

  for (int i = tid; i < 1024; i += 256) {      // sK
    int key = i >> 1, half = i & 1;
    u16x8 v = vz;
    if (key < G_) v = *(const u16x8*)(Pk + key*KD_ + half*8);
    *(u16x8*)(sK + key*24 + half*8) = v;
  }
  const unsigned short* pv = Pvt + (size_t)(h*B_ + b)*8320;
  for (int i = tid; i < 1040; i += 256)        // sVt: straight vector copy
    *(u16x8*)(sVt + i*8) = *(const u16x8*)(pv + i*8);
  for (int i = tid; i < 1040; i += 256) {      // sQ: both tiles, 4 arrays each
    int t = i / 520; int j2 = i - t*520;
    int arr = j2 / 130; int j = j2 - arr*130;
    int rr = j >> 1, half = j & 1;
    int r = (rt2*2 + t)*64 + rr;
    u16x8 v = vz;
    if (rr < 64 && r < G_) {
      bool pick = (r <= NP_);
      int w = (arr==0) ? 0 : (arr==1) ? (pick?4:8) : (arr==2) ? (pick?5:7) : (pick?3:6);
      v = *(const u16x8*)(P + ((size_t)(h*9+w)*B_ + b)*slab + (size_t)r*KD_ + half*8);
    }
    *(u16x8*)(sQ + (t*4+arr)*1040 + j*8) = v;
  }
  __syncthreads();

  unsigned short* eb = eBuf + wv*1280;

  for (int t = 0; t < 2; ++t) {
    const int r0 = (rt2*2 + t)*64;
    const unsigned short* sQt = sQ + t*4160;
    const int aoff = (wv*16 + ln)*16 + quad*8;
    bf16x8 qa  = *(const bf16x8_a*)(sQt + aoff);
    bf16x8 qp  = *(const bf16x8_a*)(sQt + 1040 + aoff);
    bf16x8 qdl = *(const bf16x8_a*)(sQt + 2080 + aoff);

    const int ra = r0 + wv*16 + ln;            // this lane's attention row
    const float rv = (ra >= 1) ? 1.f : 0.f;

    f32x4 acc = {0.f,0.f,0.f,0.f};
    float esum = 0.f;

    #pragma unroll
    for (int p = 0; p < 8; ++p) {
      const int c0 = 2*p, c1 = c0 + 1;
      score_chunk(c0, c0 <= 7, c0 >= 7, 0, sK, qa, qp, qdl, eb, rv, esum, ln, quad);
      score_chunk(c1, c1 <= 7, c1 >= 7, 1, sK, qa, qp, qdl, eb, rv, esum, ln, quad);
      #pragma unroll
      for (int u = 0; u < 2; ++u) {
        bf16x8 Ef = *(const bf16x8_a*)(eb + u*640 + ln*40 + quad*8);
        bf16x8 Vf = *(const bf16x8_a*)(sVt + ln*520 + (c0+u)*32 + quad*8);
        acc = mf(Vf, Ef, acc);                 // O^T[kd][row] += V^T * E^T
      }
    }

    esum += __shfl_xor(esum, 16);
    esum += __shfl_xor(esum, 32);

    // paired single score: 16-elem dot per row (redundant across quads)
    const unsigned short* qsp = sQt + 3120 + (wv*16 + ln)*16;
    const int kpair = (ra >= 1 && ra < G_) ? ((ra <= NP_) ? ra + NP_ : ra - NP_) : 0;
    const unsigned short* ksp = sK + kpair*24;
    u16x8 qs0 = *(const u16x8_a*)(qsp), qs1 = *(const u16x8_a*)(qsp + 8);
    u16x8 ks0 = *(const u16x8_a*)(ksp), ks1 = *(const u16x8_a*)(ksp + 8);
    float s = 0.f;
    #pragma unroll
    for (int kd = 0; kd < 8; ++kd) {
      s = fmaf(bf2f(qs0[kd]), bf2f(ks0[kd]), s);
      s = fmaf(bf2f(qs1[kd]), bf2f(ks1[kd]), s);
    }
    const float rvs = (ra >= 1 && ra < G_) ? 1.f : 0.f;
    const float esng = rvs * __expf(s);
    const float rcp = __builtin_amdgcn_rcpf(esum + esng);

    u16x4 ov;
    ov[0] = f2bf((acc[0] + esng * bf2f(sVt[(quad*4+0)*520 + kpair])) * rcp);
    ov[1] = f2bf((acc[1] + esng * bf2f(sVt[(quad*4+1)*520 + kpair])) * rcp);
    ov[2] = f2bf((acc[2] + esng * bf2f(sVt[(quad*4+2)*520 + kpair])) * rcp);
    ov[3] = f2bf((acc[3] + esng * bf2f(sVt[(quad*4+3)*520 + kpair])) * rcp);
    if (ra < G_)
      *(u16x4*)(headsb + ((size_t)(b*G_ + ra))*E_ + h*16 + quad*4) = ov;
  }
}

// ---------------- K3: out = heads_bf16(8016x128) @ W_out(128x128), MFMA -------------
// grid 126 blocks x 256 thr; 64 rows per block.
__global__ __launch_bounds__(256) void k_out(const unsigned short* __restrict__ headsb,
                                             const float* __restrict__ wout,
                                             float* __restrict__ out) {
  const int tid = threadIdx.x;
  const int lane = tid & 63;
  const int wv = tid >> 6;
  const int ln = lane & 15;
  const int quad = lane >> 4;
  const int base = blockIdx.x * 64;

  __shared__ __align__(16) unsigned short sWt[128*136];  // [e][k] transposed W_out
  for (int i = tid; i < 16384; i += 256) {
    int k = i >> 7, e = i & 127;
    sWt[e*136 + k] = f2bf(wout[i]);
  }
  __syncthreads();

  const int row = min(base + wv*16 + ln, BN_ - 1);
  bf16x8 a[4];
  #pragma unroll
  for (int ks = 0; ks < 4; ++ks)
    a[ks] = *(const bf16x8_a*)(headsb + (size_t)row*E_ + ks*32 + quad*8);

  #pragma unroll
  for (int ct = 0; ct < 8; ++ct) {
    f32x4 acc = {0.f,0.f,0.f,0.f};
    #pragma unroll
    for (int ks = 0; ks < 4; ++ks) {
      bf16x8 bb = *(const bf16x8_a*)(sWt + (ct*16 + ln)*136 + ks*32 + quad*8);
      acc = __builtin_amdgcn_mfma_f32_16x16x32_bf16(a[ks], bb, acc, 0,0,0);
    }
    #pragma unroll
    for (int g = 0; g < 4; ++g) {
      const int r = base + wv*16 + quad*4 + g;
      if (r < BN_) out[(size_t)r*E_ + ct*16 + ln] = acc[g];
    }
  }
}

extern "C" void kernel_launch(void* const* d_in, const int* in_sizes, int n_in,
                              void* d_out, int out_size, void* d_ws, size_t ws_size,
                              hipStream_t stream) {
  const float* q = (const float*)d_in[0];
  const float* w0 = (const float*)d_in[1];
  const float* w1 = (const float*)d_in[2];
  const float* w2 = (const float*)d_in[3];
  const float* w3 = (const float*)d_in[4];
  const float* w4 = (const float*)d_in[5];
  const float* w5 = (const float*)d_in[6];
  const float* w6 = (const float*)d_in[7];
  const float* w7 = (const float*)d_in[8];
  const float* w8 = (const float*)d_in[9];
  const float* wout = (const float*)d_in[10];
  float* out = (float*)d_out;

  char* ws = (char*)d_ws;
  unsigned short* wct    = (unsigned short*)(ws);              // 1152*128*2     =    294,912
  unsigned short* P      = (unsigned short*)(ws + 294912);     // 72*16*501*16*2 = 18,468,864
  unsigned short* Pvt    = (unsigned short*)(ws + 18763776);   // 128*16*520*2   =  2,129,920
  unsigned short* headsb = (unsigned short*)(ws + 20893696);   // 8016*128*2     =  2,052,096

  k_prep<<<dim3(576), dim3(256), 0, stream>>>(w0,w1,w2,w3,w4,w5,w6,w7,w8, wct, Pvt);
  k_proj<<<dim3(18, 128), dim3(256), 0, stream>>>(q, wct, P, Pvt);
  k_attn<<<dim3(4, 16, 8), dim3(256), 0, stream>>>(P, Pvt, headsb);
  k_out<<<dim3(126), dim3(256), 0, stream>>>(headsb, wout, out);
}